// Round 22
// baseline (57.367 us; speedup 1.0000x reference)
//
#include <hip/hip_runtime.h>
#include <hip/hip_bf16.h>

#define B_ 2
#define H_ 16
#define T_ 2048
#define D_ 64
#define BH (B_*H_)

typedef __attribute__((ext_vector_type(8))) short bf16x8;
typedef __attribute__((ext_vector_type(16))) float f32x16;
typedef __attribute__((ext_vector_type(4))) unsigned int u32x4;
typedef unsigned int u32;

typedef __attribute__((address_space(3))) void lds_void;
typedef __attribute__((address_space(1))) const void gbl_void;

__device__ __forceinline__ ushort f2bu(float x){
    __hip_bfloat16 h = __float2bfloat16(x);
    return __builtin_bit_cast(ushort, h);
}
__device__ __forceinline__ u32 cvtpk(float a, float b){
    u32 r; asm("v_cvt_pk_bf16_f32 %0, %1, %2" : "=v"(r) : "v"(a), "v"(b)); return r;
}
// Cross-half (lane ^ 32) reductions via permlane32_swap. Empty asm on b keeps
// it in its OWN register (round-4 lesson: coalescer self-swap bug -> NaN).
__device__ __forceinline__ float xhalf_max(float x){
    float a = x, b = x;
    asm("" : "+v"(b));
    asm("v_permlane32_swap_b32 %0, %1" : "+v"(a), "+v"(b));
    return fmaxf(a, b);
}
__device__ __forceinline__ float xhalf_sum(float x){
    float a = x, b = x;
    asm("" : "+v"(b));
    asm("v_permlane32_swap_b32 %0, %1" : "+v"(a), "+v"(b));
    return a + b;
}

// Fused prep (bodies verbatim from the rounds-2..21-proven tr_bf16):
//  blockIdx.y < 32: k f32 [D][T] -> KT bf16 [T][D], vmask'd key rows zeroed
//  blockIdx.y >= 32: v f32 [T][D] -> VT bf16 [D][T]
__global__ __launch_bounds__(256) void prep(
    const float* __restrict__ k, const float* __restrict__ v,
    const float* __restrict__ vm,
    ushort* __restrict__ KT, ushort* __restrict__ VT)
{
    __shared__ ushort tl[64][65];
    const int bh = blockIdx.x;
    const bool isK = (blockIdx.y < 32);
    const int ty = isK ? blockIdx.y : (blockIdx.y - 32);
    const int i0 = isK ? 0 : ty*64;
    const int j0 = isK ? ty*64 : 0;
    const int M = isK ? D_ : T_;
    const int N = isK ? T_ : D_;
    const float* s = (isK ? k : v) + (size_t)bh*M*N;
    ushort*      d = (isK ? KT : VT) + (size_t)bh*M*N;
    const int tid = threadIdx.x;
    const int rr = tid>>4, c4 = (tid&15)*4;
    #pragma unroll
    for (int p=0;p<4;++p){
        int a = p*16+rr;
        float4 x = *reinterpret_cast<const float4*>(&s[(size_t)(i0+a)*N + j0 + c4]);
        tl[c4+0][a]=f2bu(x.x); tl[c4+1][a]=f2bu(x.y);
        tl[c4+2][a]=f2bu(x.z); tl[c4+3][a]=f2bu(x.w);
    }
    __syncthreads();
    #pragma unroll
    for (int p=0;p<4;++p){
        int bb = p*16+rr;
        ushort4 u;
        u.x=tl[bb][c4]; u.y=tl[bb][c4+1]; u.z=tl[bb][c4+2]; u.w=tl[bb][c4+3];
        if (isK && vm[(size_t)(bh>>4)*T_ + j0 + bb] == 0.f) { u.x=0;u.y=0;u.z=0;u.w=0; }
        *reinterpret_cast<ushort4*>(&d[(size_t)(j0+bb)*M + i0 + c4]) = u;
    }
}

// Barrier-free flash attention, R15 structure + DEPTH-2 PREFETCH (T4).
// 2048 one-wave blocks (32 q-rows). TWO 16KB buffers: tile t lives in
// buf[t&1]; during step t (after frag reads drain via lgkmcnt) tile t+2 is
// staged into buf[t&1] while tile t+1 is STILL IN FLIGHT. Loop-bottom wait
// is vmcnt(16) — only t+1's 16 loads must land; t+2's stay outstanding
// (counted-vmcnt, never 0 in-loop; FIFO semantics m135-verified). Each DMA
// gets ~2 steps to land vs <1 in R15 — attacks the measured ~2000cy/step
// exposed-latency gap. LDS 32KB -> 5 blocks/CU + backfill queue.
__global__ __launch_bounds__(64, 2) void attn_fwd(
    const float* __restrict__ q, const float* __restrict__ fp,
    const float* __restrict__ hmask,
    const ushort* __restrict__ KT,   // bf16 [T][D] per bh (vmask'd rows zeroed)
    const ushort* __restrict__ VT,   // bf16 [D][T] per bh
    float* __restrict__ out)
{
    __shared__ __align__(16) ushort sbuf[2][8192];  // per-buf: K 0-4095 | V 4096-8191

    const int bid = blockIdx.x;
    const int bh = bid & (BH-1);
    const int qw = 63 - (bid >> 5);            // heavy-first, 32 rows per wave
    const int i0 = qw*32;
    const int lane = threadIdx.x & 63;
    const int col = lane & 31;
    const int hi  = lane >> 5;

    const ushort* KTb = KT + (size_t)bh*T_*D_;
    const ushort* VTb = VT + (size_t)bh*T_*D_;

    const float hmv = hmask[(size_t)(bh>>4)*T_ + i0 + col];
    const float sscale = 1.4426950408889634f / fp[0];
    const float qs = (hmv != 0.f) ? sscale : 0.f;   // hmask==0 -> row scores 0
    const float NINF = -__builtin_inff();

    // Q B-frags (pre-scaled): B[d = dc*16+hi*8+e][col]   (rounds 3-21 proven)
    const float* qp = q + (size_t)bh*T_*D_ + (size_t)(i0+col)*D_ + hi*8;
    bf16x8 qf[4];
    #pragma unroll
    for (int dc=0; dc<4; ++dc){
        float4 x0 = *reinterpret_cast<const float4*>(qp + dc*16);
        float4 x1 = *reinterpret_cast<const float4*>(qp + dc*16 + 4);
        u32x4 dw;
        dw[0] = cvtpk(x0.x*qs, x0.y*qs);
        dw[1] = cvtpk(x0.z*qs, x0.w*qs);
        dw[2] = cvtpk(x1.x*qs, x1.y*qs);
        dw[3] = cvtpk(x1.z*qs, x1.w*qs);
        qf[dc] = __builtin_bit_cast(bf16x8, dw);
    }

    float m_run = 0.f, l_run = 0.f;   // defer-max: 0-init safe (R12-21 proven)
    f32x16 o0, o1;
    #pragma unroll
    for (int r=0;r<16;++r){ o0[r]=0.f; o1[r]=0.f; }

    const unsigned uoff = (unsigned)(lane*16);       // staging byte cursor
    const unsigned swz = ((unsigned)(col&7)) << 4;   // frag-read swizzle

    // stage tile t into buffer b (R10-21-proven addressing, 16 x 1KB loads)
    auto stage = [&](int b, int t){
        char* ldsK = (char*)&sbuf[b][0];
        char* ldsV = (char*)&sbuf[b][4096];
        const char* kbase = (const char*)KTb + (size_t)t*8192;
        #pragma unroll
        for (int i=0;i<8;++i){
            const unsigned u = i*1024u + uoff;
            const unsigned su = u ^ (((u>>7)&7u)<<4);
            __builtin_amdgcn_global_load_lds(
                (gbl_void*)(kbase + su),
                (lds_void*)(ldsK + i*1024), 16, 0, 0);
        }
        #pragma unroll
        for (int i=0;i<8;++i){
            const unsigned u = i*1024u + uoff;
            const unsigned dR = u>>7;
            const unsigned inr = (u&127u) ^ ((dR&7u)<<4);
            const char* src = (const char*)VTb + (size_t)dR*(T_*2) + (size_t)t*128 + inr;
            __builtin_amdgcn_global_load_lds(
                (gbl_void*)src,
                (lds_void*)(ldsV + i*1024), 16, 0, 0);
        }
    };

    const int n = (qw >> 1) + 1;     // tiles 0..n-1 cover keys <= i0+31
    stage(0, 0);
    if (n > 1) {
        stage(1, 1);                 // 32 outstanding; wait until tile0's 16 done
        asm volatile("s_waitcnt vmcnt(16)" ::: "memory");
    } else {
        asm volatile("s_waitcnt vmcnt(0)" ::: "memory");
    }

    for (int t=0; t<n; ++t){
        const int j0 = t*64;
        const int b = t & 1;

        // K+V frags LDS -> registers (R10-21-proven addressing)
        const char* sKb = (const char*)&sbuf[b][0];
        bf16x8 kf[8];
        #pragma unroll
        for (int kt=0;kt<2;++kt)
            #pragma unroll
            for (int dc=0;dc<4;++dc)
                kf[kt*4+dc] = *reinterpret_cast<const bf16x8*>(
                    sKb + (((unsigned)(kt*4096 + dc*32 + col*128 + hi*16)) ^ swz));
        const char* sVb = (const char*)&sbuf[b][4096];
        bf16x8 vf[8];
        #pragma unroll
        for (int f=0;f<8;++f)
            vf[f] = *reinterpret_cast<const bf16x8*>(
                sVb + (((unsigned)((f>>2)*4096 + (f&3)*32 + col*128 + hi*16)) ^ swz));

        // my LDS reads complete -> buf[b] free; stage tile t+2 into it while
        // tile t+1 (staged last step) is still in flight. rule #18 fence.
        asm volatile("s_waitcnt lgkmcnt(0)" ::: "memory");
        __builtin_amdgcn_sched_barrier(0);
        if (t+2 < n) stage(b, t+2);

        // S^T = K Q^T
        f32x16 s0, s1;
        #pragma unroll
        for (int r=0;r<16;++r){ s0[r]=0.f; s1[r]=0.f; }
        #pragma unroll
        for (int dc=0;dc<4;++dc){
            s0 = __builtin_amdgcn_mfma_f32_32x32x16_bf16(kf[dc],   qf[dc], s0, 0,0,0);
            s1 = __builtin_amdgcn_mfma_f32_32x32x16_bf16(kf[4+dc], qf[dc], s1, 0,0,0);
        }

        // causal -inf only on the diagonal tile. masked_fill(s==0, 1e-10) is a
        // numeric no-op in fp32 (R12-proven): masked scores are exactly 0.
        if (j0 + 63 > i0) {
            const int th0 = i0 + col - j0 - 4*hi;
            const int th1 = th0 - 32;
            #pragma unroll
            for (int r=0;r<16;++r){
                const int basr = (r&3) + 8*(r>>2);
                s0[r] = (basr <= th0) ? s0[r] : NINF;
                s1[r] = (basr <= th1) ? s1[r] : NINF;
            }
        }

        // row max (tree + cross-half), defer-max rescale (R12-21 proven)
        float tm[8];
        #pragma unroll
        for (int i=0;i<8;++i)
            tm[i] = fmaxf(fmaxf(s0[2*i], s0[2*i+1]), fmaxf(s1[2*i], s1[2*i+1]));
        #pragma unroll
        for (int st=4; st>=1; st>>=1)
            #pragma unroll
            for (int i=0;i<st;++i) tm[i] = fmaxf(tm[i], tm[i+st]);
        const float mt = xhalf_max(tm[0]);
        if (__any(!(mt <= m_run + 8.0f))) {
            const float mn = fmaxf(m_run, mt);
            const float fac = __builtin_amdgcn_exp2f(m_run - mn);
            m_run = mn; l_run *= fac;
            #pragma unroll
            for (int r=0;r<16;++r){ o0[r]*=fac; o1[r]*=fac; }
        }

        // P = exp2(s - m_run), row-sum via tree + cross-half
        float tsum[8];
        #pragma unroll
        for (int i=0;i<8;++i){
            float p00 = __builtin_amdgcn_exp2f(s0[2*i]   - m_run);
            float p01 = __builtin_amdgcn_exp2f(s0[2*i+1] - m_run);
            float p10 = __builtin_amdgcn_exp2f(s1[2*i]   - m_run);
            float p11 = __builtin_amdgcn_exp2f(s1[2*i+1] - m_run);
            s0[2*i]=p00; s0[2*i+1]=p01; s1[2*i]=p10; s1[2*i+1]=p11;
            tsum[i] = (p00+p01) + (p10+p11);
        }
        #pragma unroll
        for (int st=4; st>=1; st>>=1)
            #pragma unroll
            for (int i=0;i<st;++i) tsum[i] += tsum[i+st];
        l_run += xhalf_sum(tsum[0]);

        // P -> bf16 B-frags (rounds 3-21 proven)
        bf16x8 pb[4];
        #pragma unroll
        for (int c2=0;c2<4;++c2){
            const f32x16& ps = (c2<2) ? s0 : s1;
            const int rb = (c2&1)*8;
            u32 a0 = cvtpk(ps[rb+0], ps[rb+1]);
            u32 a1 = cvtpk(ps[rb+2], ps[rb+3]);
            u32 a2 = cvtpk(ps[rb+4], ps[rb+5]);
            u32 a3 = cvtpk(ps[rb+6], ps[rb+7]);
            asm("v_permlane32_swap_b32 %0, %1" : "+v"(a0), "+v"(a2));
            asm("v_permlane32_swap_b32 %0, %1" : "+v"(a1), "+v"(a3));
            u32x4 dw; dw[0]=a0; dw[1]=a1; dw[2]=a2; dw[3]=a3;
            pb[c2] = __builtin_bit_cast(bf16x8, dw);
        }

        // O^T += V^T P^T  (all operands in registers)
        #pragma unroll
        for (int c2=0;c2<4;++c2){
            o0 = __builtin_amdgcn_mfma_f32_32x32x16_bf16(vf[c2],   pb[c2], o0, 0,0,0);
            o1 = __builtin_amdgcn_mfma_f32_32x32x16_bf16(vf[4+c2], pb[c2], o1, 0,0,0);
        }

        // wait only for tile t+1 (16 oldest); t+2's loads stay in flight
        if (t+1 < n) {
            if (t+2 < n) asm volatile("s_waitcnt vmcnt(16)" ::: "memory");
            else         asm volatile("s_waitcnt vmcnt(0)"  ::: "memory");
        }
    }

    // epilogue: O = O^T / l, float4 stores (rounds 10-21 proven)
    const float rinv = 1.0f / l_run;
    float* op = out + (size_t)bh*T_*D_ + (size_t)(i0+col)*D_;
    #pragma unroll
    for (int q4=0;q4<4;++q4){
        float4 a = {o0[4*q4]*rinv, o0[4*q4+1]*rinv, o0[4*q4+2]*rinv, o0[4*q4+3]*rinv};
        *reinterpret_cast<float4*>(op + 8*q4 + 4*hi) = a;
        float4 b = {o1[4*q4]*rinv, o1[4*q4+1]*rinv, o1[4*q4+2]*rinv, o1[4*q4+3]*rinv};
        *reinterpret_cast<float4*>(op + 32 + 8*q4 + 4*hi) = b;
    }
}

extern "C" void kernel_launch(void* const* d_in, const int* in_sizes, int n_in,
                              void* d_out, int out_size, void* d_ws, size_t ws_size,
                              hipStream_t stream) {
    const float* q  = (const float*)d_in[0];
    const float* k  = (const float*)d_in[1];
    const float* v  = (const float*)d_in[2];
    const float* f  = (const float*)d_in[3];
    const float* vm = (const float*)d_in[4];
    const float* hm = (const float*)d_in[5];
    float* out = (float*)d_out;

    const size_t slab = (size_t)BH * T_ * D_;
    ushort* KT = (ushort*)d_ws;
    ushort* VT = KT + slab;

    // fused K+V prep (proven bodies, one launch)
    hipLaunchKernelGGL(prep, dim3(BH, 64), dim3(256), 0, stream, k, v, vm, KT, VT);

    dim3 grid(2048);   // 32 bh x 64 q-waves, heavy-first; 1 wave per block
    dim3 block(64);
    hipLaunchKernelGGL(attn_fwd, grid, block, 0, stream, q, f, hm, KT, VT, out);
}

// Round 23
// 51.510 us; speedup vs baseline: 1.1137x; 1.1137x over previous
//
#include <hip/hip_runtime.h>
#include <hip/hip_bf16.h>

#define B_ 2
#define H_ 16
#define T_ 2048
#define D_ 64
#define BH (B_*H_)

typedef __attribute__((ext_vector_type(8))) short bf16x8;
typedef __attribute__((ext_vector_type(16))) float f32x16;
typedef __attribute__((ext_vector_type(4))) unsigned int u32x4;
typedef unsigned int u32;

typedef __attribute__((address_space(3))) void lds_void;
typedef __attribute__((address_space(1))) const void gbl_void;

__device__ __forceinline__ ushort f2bu(float x){
    __hip_bfloat16 h = __float2bfloat16(x);
    return __builtin_bit_cast(ushort, h);
}
__device__ __forceinline__ u32 cvtpk(float a, float b){
    u32 r; asm("v_cvt_pk_bf16_f32 %0, %1, %2" : "=v"(r) : "v"(a), "v"(b)); return r;
}
// Cross-half (lane ^ 32) reductions via permlane32_swap. Empty asm on b keeps
// it in its OWN register (round-4 lesson: coalescer self-swap bug -> NaN).
__device__ __forceinline__ float xhalf_max(float x){
    float a = x, b = x;
    asm("" : "+v"(b));
    asm("v_permlane32_swap_b32 %0, %1" : "+v"(a), "+v"(b));
    return fmaxf(a, b);
}
__device__ __forceinline__ float xhalf_sum(float x){
    float a = x, b = x;
    asm("" : "+v"(b));
    asm("v_permlane32_swap_b32 %0, %1" : "+v"(a), "+v"(b));
    return a + b;
}

// Fused prep:
//  blockIdx.y < 32: k f32 [D][T] -> KT bf16 [T][D], vmask'd key rows zeroed
//  blockIdx.y >= 32: v f32 [T][D] -> VT bf16 [D][T]
__global__ __launch_bounds__(256) void prep(
    const float* __restrict__ k, const float* __restrict__ v,
    const float* __restrict__ vm,
    ushort* __restrict__ KT, ushort* __restrict__ VT)
{
    __shared__ ushort tl[64][65];
    const int bh = blockIdx.x;
    const bool isK = (blockIdx.y < 32);
    const int ty = isK ? blockIdx.y : (blockIdx.y - 32);
    const int i0 = isK ? 0 : ty*64;
    const int j0 = isK ? ty*64 : 0;
    const int M = isK ? D_ : T_;
    const int N = isK ? T_ : D_;
    const float* s = (isK ? k : v) + (size_t)bh*M*N;
    ushort*      d = (isK ? KT : VT) + (size_t)bh*M*N;
    const int tid = threadIdx.x;
    const int rr = tid>>4, c4 = (tid&15)*4;
    #pragma unroll
    for (int p=0;p<4;++p){
        int a = p*16+rr;
        float4 x = *reinterpret_cast<const float4*>(&s[(size_t)(i0+a)*N + j0 + c4]);
        tl[c4+0][a]=f2bu(x.x); tl[c4+1][a]=f2bu(x.y);
        tl[c4+2][a]=f2bu(x.z); tl[c4+3][a]=f2bu(x.w);
    }
    __syncthreads();
    #pragma unroll
    for (int p=0;p<4;++p){
        int bb = p*16+rr;
        ushort4 u;
        u.x=tl[bb][c4]; u.y=tl[bb][c4+1]; u.z=tl[bb][c4+2]; u.w=tl[bb][c4+3];
        if (isK && vm[(size_t)(bh>>4)*T_ + j0 + bb] == 0.f) { u.x=0;u.y=0;u.z=0;u.w=0; }
        *reinterpret_cast<ushort4*>(&d[(size_t)(j0+bb)*M + i0 + c4]) = u;
    }
}

// Barrier-free flash attention, TLP-first (best measured configuration:
// 42us attn / 51.5us total, R15). 2048 one-wave blocks (32 q-rows each),
// SINGLE 16KB LDS buffer -> 8 blocks/CU resident (2 independent waves/SIMD).
// Prefetch via reg-staging: K+V frags LDS->regs, lgkmcnt(0)+sched_barrier(0)
// (rule #18), THEN stage(t+1) into the same buffer, compute from registers,
// vmcnt(0) at loop bottom. Swapped-operand QK^T (lane-local softmax),
// cvt_pk+permlane P conversion, defer-max (THR=8), no-mask trick
// (masked_fill(s==0,1e-10) is a numeric no-op in fp32 given zeroed K/Q).
__global__ __launch_bounds__(64, 2) void attn_fwd(
    const float* __restrict__ q, const float* __restrict__ fp,
    const float* __restrict__ hmask,
    const ushort* __restrict__ KT,   // bf16 [T][D] per bh (vmask'd rows zeroed)
    const ushort* __restrict__ VT,   // bf16 [D][T] per bh
    float* __restrict__ out)
{
    __shared__ __align__(16) ushort sbuf[8192];  // K:0-4095 | V:4096-8191

    const int bid = blockIdx.x;
    const int bh = bid & (BH-1);
    const int qw = 63 - (bid >> 5);            // heavy-first, 32 rows per wave
    const int i0 = qw*32;
    const int lane = threadIdx.x & 63;
    const int col = lane & 31;
    const int hi  = lane >> 5;

    const ushort* KTb = KT + (size_t)bh*T_*D_;
    const ushort* VTb = VT + (size_t)bh*T_*D_;

    const float hmv = hmask[(size_t)(bh>>4)*T_ + i0 + col];
    const float sscale = 1.4426950408889634f / fp[0];
    const float qs = (hmv != 0.f) ? sscale : 0.f;   // hmask==0 -> row scores 0
    const float NINF = -__builtin_inff();

    // Q B-frags (pre-scaled): B[d = dc*16+hi*8+e][col]
    const float* qp = q + (size_t)bh*T_*D_ + (size_t)(i0+col)*D_ + hi*8;
    bf16x8 qf[4];
    #pragma unroll
    for (int dc=0; dc<4; ++dc){
        float4 x0 = *reinterpret_cast<const float4*>(qp + dc*16);
        float4 x1 = *reinterpret_cast<const float4*>(qp + dc*16 + 4);
        u32x4 dw;
        dw[0] = cvtpk(x0.x*qs, x0.y*qs);
        dw[1] = cvtpk(x0.z*qs, x0.w*qs);
        dw[2] = cvtpk(x1.x*qs, x1.y*qs);
        dw[3] = cvtpk(x1.z*qs, x1.w*qs);
        qf[dc] = __builtin_bit_cast(bf16x8, dw);
    }

    float m_run = 0.f, l_run = 0.f;   // defer-max: 0-init safe
    f32x16 o0, o1;
    #pragma unroll
    for (int r=0;r<16;++r){ o0[r]=0.f; o1[r]=0.f; }

    const unsigned uoff = (unsigned)(lane*16);       // staging byte cursor
    const unsigned swz = ((unsigned)(col&7)) << 4;   // frag-read swizzle

    // stage tile t into THE buffer (16 x 1KB coalesced global_load_lds)
    auto stage = [&](int t){
        char* ldsK = (char*)&sbuf[0];
        char* ldsV = (char*)&sbuf[4096];
        const char* kbase = (const char*)KTb + (size_t)t*8192;
        #pragma unroll
        for (int i=0;i<8;++i){
            const unsigned u = i*1024u + uoff;
            const unsigned su = u ^ (((u>>7)&7u)<<4);
            __builtin_amdgcn_global_load_lds(
                (gbl_void*)(kbase + su),
                (lds_void*)(ldsK + i*1024), 16, 0, 0);
        }
        #pragma unroll
        for (int i=0;i<8;++i){
            const unsigned u = i*1024u + uoff;
            const unsigned dR = u>>7;
            const unsigned inr = (u&127u) ^ ((dR&7u)<<4);
            const char* src = (const char*)VTb + (size_t)dR*(T_*2) + (size_t)t*128 + inr;
            __builtin_amdgcn_global_load_lds(
                (gbl_void*)src,
                (lds_void*)(ldsV + i*1024), 16, 0, 0);
        }
    };

    const int n = (qw >> 1) + 1;     // tiles 0..n-1 cover keys <= i0+31
    stage(0);
    asm volatile("s_waitcnt vmcnt(0)" ::: "memory");

    for (int t=0; t<n; ++t){
        const int j0 = t*64;

        // K+V frags LDS -> registers
        const char* sKb = (const char*)&sbuf[0];
        bf16x8 kf[8];
        #pragma unroll
        for (int kt=0;kt<2;++kt)
            #pragma unroll
            for (int dc=0;dc<4;++dc)
                kf[kt*4+dc] = *reinterpret_cast<const bf16x8*>(
                    sKb + (((unsigned)(kt*4096 + dc*32 + col*128 + hi*16)) ^ swz));
        const char* sVb = (const char*)&sbuf[4096];
        bf16x8 vf[8];
        #pragma unroll
        for (int f=0;f<8;++f)
            vf[f] = *reinterpret_cast<const bf16x8*>(
                sVb + (((unsigned)((f>>2)*4096 + (f&3)*32 + col*128 + hi*16)) ^ swz));

        // all LDS reads complete -> safe to overwrite buffer with next tile.
        asm volatile("s_waitcnt lgkmcnt(0)" ::: "memory");
        __builtin_amdgcn_sched_barrier(0);
        if (t+1 < n) stage(t+1);   // DMA latency hides under compute below

        // S^T = K Q^T
        f32x16 s0, s1;
        #pragma unroll
        for (int r=0;r<16;++r){ s0[r]=0.f; s1[r]=0.f; }
        #pragma unroll
        for (int dc=0;dc<4;++dc){
            s0 = __builtin_amdgcn_mfma_f32_32x32x16_bf16(kf[dc],   qf[dc], s0, 0,0,0);
            s1 = __builtin_amdgcn_mfma_f32_32x32x16_bf16(kf[4+dc], qf[dc], s1, 0,0,0);
        }

        // causal -inf only on the diagonal tile
        if (j0 + 63 > i0) {
            const int th0 = i0 + col - j0 - 4*hi;
            const int th1 = th0 - 32;
            #pragma unroll
            for (int r=0;r<16;++r){
                const int basr = (r&3) + 8*(r>>2);
                s0[r] = (basr <= th0) ? s0[r] : NINF;
                s1[r] = (basr <= th1) ? s1[r] : NINF;
            }
        }

        // row max (tree + cross-half), defer-max rescale
        float tm[8];
        #pragma unroll
        for (int i=0;i<8;++i)
            tm[i] = fmaxf(fmaxf(s0[2*i], s0[2*i+1]), fmaxf(s1[2*i], s1[2*i+1]));
        #pragma unroll
        for (int st=4; st>=1; st>>=1)
            #pragma unroll
            for (int i=0;i<st;++i) tm[i] = fmaxf(tm[i], tm[i+st]);
        const float mt = xhalf_max(tm[0]);
        if (__any(!(mt <= m_run + 8.0f))) {
            const float mn = fmaxf(m_run, mt);
            const float fac = __builtin_amdgcn_exp2f(m_run - mn);
            m_run = mn; l_run *= fac;
            #pragma unroll
            for (int r=0;r<16;++r){ o0[r]*=fac; o1[r]*=fac; }
        }

        // P = exp2(s - m_run), row-sum via tree + cross-half
        float tsum[8];
        #pragma unroll
        for (int i=0;i<8;++i){
            float p00 = __builtin_amdgcn_exp2f(s0[2*i]   - m_run);
            float p01 = __builtin_amdgcn_exp2f(s0[2*i+1] - m_run);
            float p10 = __builtin_amdgcn_exp2f(s1[2*i]   - m_run);
            float p11 = __builtin_amdgcn_exp2f(s1[2*i+1] - m_run);
            s0[2*i]=p00; s0[2*i+1]=p01; s1[2*i]=p10; s1[2*i+1]=p11;
            tsum[i] = (p00+p01) + (p10+p11);
        }
        #pragma unroll
        for (int st=4; st>=1; st>>=1)
            #pragma unroll
            for (int i=0;i<st;++i) tsum[i] += tsum[i+st];
        l_run += xhalf_sum(tsum[0]);

        // P -> bf16 B-frags (cvt_pk + permlane32_swap, no LDS)
        bf16x8 pb[4];
        #pragma unroll
        for (int c2=0;c2<4;++c2){
            const f32x16& ps = (c2<2) ? s0 : s1;
            const int rb = (c2&1)*8;
            u32 a0 = cvtpk(ps[rb+0], ps[rb+1]);
            u32 a1 = cvtpk(ps[rb+2], ps[rb+3]);
            u32 a2 = cvtpk(ps[rb+4], ps[rb+5]);
            u32 a3 = cvtpk(ps[rb+6], ps[rb+7]);
            asm("v_permlane32_swap_b32 %0, %1" : "+v"(a0), "+v"(a2));
            asm("v_permlane32_swap_b32 %0, %1" : "+v"(a1), "+v"(a3));
            u32x4 dw; dw[0]=a0; dw[1]=a1; dw[2]=a2; dw[3]=a3;
            pb[c2] = __builtin_bit_cast(bf16x8, dw);
        }

        // O^T += V^T P^T  (all operands in registers)
        #pragma unroll
        for (int c2=0;c2<4;++c2){
            o0 = __builtin_amdgcn_mfma_f32_32x32x16_bf16(vf[c2],   pb[c2], o0, 0,0,0);
            o1 = __builtin_amdgcn_mfma_f32_32x32x16_bf16(vf[4+c2], pb[c2], o1, 0,0,0);
        }

        asm volatile("s_waitcnt vmcnt(0)" ::: "memory");  // next tile landed
    }

    // epilogue: O = O^T / l, float4 stores
    const float rinv = 1.0f / l_run;
    float* op = out + (size_t)bh*T_*D_ + (size_t)(i0+col)*D_;
    #pragma unroll
    for (int q4=0;q4<4;++q4){
        float4 a = {o0[4*q4]*rinv, o0[4*q4+1]*rinv, o0[4*q4+2]*rinv, o0[4*q4+3]*rinv};
        *reinterpret_cast<float4*>(op + 8*q4 + 4*hi) = a;
        float4 b = {o1[4*q4]*rinv, o1[4*q4+1]*rinv, o1[4*q4+2]*rinv, o1[4*q4+3]*rinv};
        *reinterpret_cast<float4*>(op + 32 + 8*q4 + 4*hi) = b;
    }
}

extern "C" void kernel_launch(void* const* d_in, const int* in_sizes, int n_in,
                              void* d_out, int out_size, void* d_ws, size_t ws_size,
                              hipStream_t stream) {
    const float* q  = (const float*)d_in[0];
    const float* k  = (const float*)d_in[1];
    const float* v  = (const float*)d_in[2];
    const float* f  = (const float*)d_in[3];
    const float* vm = (const float*)d_in[4];
    const float* hm = (const float*)d_in[5];
    float* out = (float*)d_out;

    const size_t slab = (size_t)BH * T_ * D_;
    ushort* KT = (ushort*)d_ws;
    ushort* VT = KT + slab;

    // fused K+V prep (one launch)
    hipLaunchKernelGGL(prep, dim3(BH, 64), dim3(256), 0, stream, k, v, vm, KT, VT);

    dim3 grid(2048);   // 32 bh x 64 q-waves, heavy-first; 1 wave per block
    dim3 block(64);
    hipLaunchKernelGGL(attn_fwd, grid, block, 0, stream, q, f, hm, KT, VT, out);
}